// Round 9
// baseline (193.950 us; speedup 1.0000x reference)
//
#include <hip/hip_runtime.h>

// 7x7 conv, stride 1, pad 3, on 64 x 512 x 512 fp32 (single channel).
// out[n,y,x] = sum_{ky,kx} x[n, y+ky-3, x+kx-3] * w[ky,kx]
//
// R8: rolling-FIR streaming. Each thread computes a 4(x) x 16(y) column strip,
// walking down the image: per input row, 3 contiguous float4 loads (12-col
// window), accumulate into a 7-slot ring of output-row accumulators
// (input row gy contributes ky=6-d to output row gy-3+d), then store + zero
// the completed row. Each input byte is read ONCE per strip (fetch ~ 22/16 x
// input), no LDS (R7: DS pipe ~55% of cycles), no barrier. sched_barrier(0)
// per row prevents the full-unroll load-hoist spill that killed R3/R5
// (WRITE_SIZE 5x output); default VGPR budget (128) this time, live ~60.

#define IMG_W 512
#define IMG_H 512
#define NIMG  64
#define HS    16      // output rows per thread (strip height)
#define HALO  3

__global__ __launch_bounds__(256, 4) void conv7x7_kernel(
    const float* __restrict__ x,
    const float* __restrict__ wgt,
    float* __restrict__ out)
{
    const int tid = threadIdx.x;
    // 128 threads across x (128*4 = 512 = full row); 2 strips per block in y.
    const int ox = (tid & 127) * 4;
    const int sy = tid >> 7;
    const int oy = (blockIdx.x * 2 + sy) * HS;
    const int n  = blockIdx.y;

    const float* img = x + (size_t)n * (IMG_W * IMG_H);
    float*       o   = out + (size_t)n * (IMG_W * IMG_H);

    // weights: wave-uniform -> SGPRs (statically indexed after unroll)
    float w[49];
    #pragma unroll
    for (int i = 0; i < 49; ++i) w[i] = wgt[i];

    // x-border predicates (all-or-nothing per aligned float4):
    // left  f4 = cols [ox-4, ox)   -> OOB only when ox == 0
    // right f4 = cols [ox+4, ox+8) -> OOB only when ox == 508
    const bool lval = (ox != 0);
    const bool rval = (ox + 7 < IMG_W);

    // ring of 7 partial output rows; slot = (output row within strip) % 7
    float acc[7][4] = {};
    const float4 z4 = make_float4(0.f, 0.f, 0.f, 0.f);

    #pragma unroll
    for (int t = 0; t < HS + 2 * HALO; ++t) {   // 22 input rows
        const int gy = oy - HALO + t;
        const bool yv = (unsigned)gy < IMG_H;
        const float* rp = &img[(size_t)gy * IMG_W + ox];
        const float4 a  = (yv && lval) ? *(const float4*)(rp - 4) : z4;
        const float4 b  = yv           ? *(const float4*)(rp)     : z4;
        const float4 c4 = (yv && rval) ? *(const float4*)(rp + 4) : z4;
        // row[tt] = input col ox-4+tt (tt = 0..11 contiguous).
        // Output col ox+cc, tap kx needs col ox+cc+kx-3 -> tt = cc+kx+1.
        const float row[12] = { a.x, a.y, a.z, a.w,
                                b.x, b.y, b.z, b.w,
                                c4.x, c4.y, c4.z, c4.w };

        // input row gy contributes to output rows orow = t-6+d (d=0..6),
        // with ky = 6-d; all indices compile-time after unroll.
        #pragma unroll
        for (int d = 0; d < 7; ++d) {
            const int orow = t - 6 + d;
            if (orow >= 0 && orow < HS) {
                const int ky   = 6 - d;
                const int slot = orow % 7;
                #pragma unroll
                for (int kx = 0; kx < 7; ++kx) {
                    const float wv = w[ky * 7 + kx];
                    #pragma unroll
                    for (int cc = 0; cc < 4; ++cc)
                        acc[slot][cc] = fmaf(row[cc + kx + 1], wv, acc[slot][cc]);
                }
            }
        }

        // output row t-6 just received its last (ky=6) contribution -> store.
        if (t >= 6) {
            const int orow = t - 6;
            const int slot = orow % 7;
            float4 v = make_float4(acc[slot][0], acc[slot][1],
                                   acc[slot][2], acc[slot][3]);
            *(float4*)&o[(size_t)(oy + orow) * IMG_W + ox] = v;
            #pragma unroll
            for (int cc = 0; cc < 4; ++cc) acc[slot][cc] = 0.f;
        }

        // Fence: loads of row t+1 may not hoist above row t's FMAs.
        // Keeps live set ~60 VGPR -> no scratch spill at default budget.
        __builtin_amdgcn_sched_barrier(0);
    }
}

extern "C" void kernel_launch(void* const* d_in, const int* in_sizes, int n_in,
                              void* d_out, int out_size, void* d_ws, size_t ws_size,
                              hipStream_t stream)
{
    const float* x   = (const float*)d_in[0];
    const float* wgt = (const float*)d_in[1];
    float* out       = (float*)d_out;

    // y: 512 rows / (2 strips * 16 rows) = 16; images in grid.y -> 1024 blocks
    dim3 grid(IMG_H / (2 * HS), NIMG, 1);
    conv7x7_kernel<<<grid, 256, 0, stream>>>(x, wgt, out);
}